// Round 6
// baseline (521.241 us; speedup 1.0000x reference)
//
#include <hip/hip_runtime.h>
#include <hip/hip_bf16.h>

typedef unsigned short u16;
typedef short bf16x8 __attribute__((ext_vector_type(8)));   // 8 bf16 = 4 VGPRs
typedef float f32x4 __attribute__((ext_vector_type(4)));

#define SS_PTS 2048

// workspace byte offsets (all 16B-aligned)
#define OFF_IDX   0ULL         // int  [65536*3]
#define OFF_W     786432ULL    // f32  [65536*3]
#define OFF_WT1B  1572864ULL   // bf16 [256][320]
#define OFF_WT2B  1736704ULL   // bf16 [128][256]
#define OFF_ST1   1802240ULL   // f32  [512]
#define OFF_ST2   1804288ULL   // f32  [256]
#define OFF_P1    1805312ULL   // f32  [1024][512]
#define OFF_P2    3902464ULL   // f32  [1024][256]
#define OFF_H1    4950016ULL   // bf16 tiled [8][65536][32]
#define OFF_H2    38504448ULL  // bf16 [65536][128]; ALSO G [16384][256] bf16
                               // (G consumed by gemm1 before gemm2 writes h2)

__device__ __forceinline__ u16 f2bf(float x) {
    union { __hip_bfloat16 h; u16 u; } cv;
    cv.h = __float2bfloat16(x);
    return cv.u;
}
__device__ __forceinline__ float bf2f(u16 u) {
    union { unsigned int i; float f; } cv;
    cv.i = ((unsigned int)u) << 16;
    return cv.f;
}
__device__ __forceinline__ float4 pack8(const float* v) {
    union { u16 u[8]; float4 f; } pk;
    #pragma unroll
    for (int j = 0; j < 8; ++j) pk.u[j] = f2bf(v[j]);
    return pk.f;
}

// ---------------------------------------------------------------- prep: W -> bf16
__global__ __launch_bounds__(256) void prep_kernel(
    const float* __restrict__ W1, const float* __restrict__ W2,
    u16* __restrict__ wt1b, u16* __restrict__ wt2b) {
    int i = blockIdx.x * 256 + threadIdx.x;
    if (i < 81920) wt1b[i] = f2bf(W1[i]);
    if (i < 32768) wt2b[i] = f2bf(W2[i]);
}

// ---------------------------------------------------------------- GEMM0
// G[16384][256] = points2[16384][256] @ W1b^T  (W1b = wt1b cols 64..319)
// 64 rows x 256 cols per block, grid 256. A-frags direct from global fp32.
__global__ __launch_bounds__(256) void gemm0_kernel(
    const float* __restrict__ points2, const u16* __restrict__ wt1b,
    u16* __restrict__ G) {
    __shared__ __align__(16) u16 Bs[8192];   // 256 rows x 32 k, XOR-swizzled

    int t = threadIdx.x, bx = blockIdx.x;
    int R0 = bx * 64;
    int w = t >> 6, l = t & 63, l15 = l & 15, q = l >> 4;
    int wr = (w >> 1) * 32, wc = (w & 1) * 128;
    int bm = t >> 1, bh = t & 1;
    int sb0 = (bm >> 1) & 3, sb1 = ((bm + 128) >> 1) & 3;
    const u16* wsrc0 = wt1b + (size_t)bm * 320 + 64 + bh * 16;
    const u16* wsrc1 = wt1b + (size_t)(bm + 128) * 320 + 64 + bh * 16;

    float4 pb0 = ((const float4*)wsrc0)[0], pb1 = ((const float4*)wsrc0)[1];
    float4 pb2 = ((const float4*)wsrc1)[0], pb3 = ((const float4*)wsrc1)[1];

    f32x4 acc[2][8];
    #pragma unroll
    for (int i = 0; i < 2; ++i)
        #pragma unroll
        for (int j = 0; j < 8; ++j) acc[i][j] = (f32x4){0.f, 0.f, 0.f, 0.f};

    #pragma unroll
    for (int kb = 0; kb < 8; ++kb) {
        *(float4*)&Bs[bm * 32 + (((bh * 2 + 0) ^ sb0) << 3)] = pb0;
        *(float4*)&Bs[bm * 32 + (((bh * 2 + 1) ^ sb0) << 3)] = pb1;
        *(float4*)&Bs[(bm + 128) * 32 + (((bh * 2 + 0) ^ sb1) << 3)] = pb2;
        *(float4*)&Bs[(bm + 128) * 32 + (((bh * 2 + 1) ^ sb1) << 3)] = pb3;
        __syncthreads();
        if (kb < 7) {
            pb0 = ((const float4*)(wsrc0 + (kb + 1) * 32))[0];
            pb1 = ((const float4*)(wsrc0 + (kb + 1) * 32))[1];
            pb2 = ((const float4*)(wsrc1 + (kb + 1) * 32))[0];
            pb3 = ((const float4*)(wsrc1 + (kb + 1) * 32))[1];
        }
        union uf { float4 f; bf16x8 v; };
        uf af[2], bf8[8];
        #pragma unroll
        for (int fi = 0; fi < 2; ++fi) {
            int ml = wr + fi * 16 + l15;
            const float* s = points2 + (size_t)(R0 + ml) * 256 + kb * 32 + q * 8;
            float4 x0 = ((const float4*)s)[0], x1 = ((const float4*)s)[1];
            float va[8] = {x0.x, x0.y, x0.z, x0.w, x1.x, x1.y, x1.z, x1.w};
            af[fi].f = pack8(va);
        }
        #pragma unroll
        for (int fj = 0; fj < 8; ++fj) {
            int nl = wc + fj * 16 + l15;
            bf8[fj].f = *(const float4*)&Bs[nl * 32 + ((q ^ ((nl >> 1) & 3)) << 3)];
        }
        #pragma unroll
        for (int fi = 0; fi < 2; ++fi)
            #pragma unroll
            for (int fj = 0; fj < 8; ++fj)
                acc[fi][fj] = __builtin_amdgcn_mfma_f32_16x16x32_bf16(
                    bf8[fj].v, af[fi].v, acc[fi][fj], 0, 0, 0);
        __syncthreads();
    }

    #pragma unroll
    for (int fi = 0; fi < 2; ++fi) {
        int rg = R0 + wr + fi * 16 + l15;
        #pragma unroll
        for (int fj = 0; fj < 8; ++fj) {
            int cl = wc + fj * 16 + q * 4;
            union { u16 u[4]; float2 f; } pk;
            #pragma unroll
            for (int i = 0; i < 4; ++i) pk.u[i] = f2bf(acc[fi][fj][i]);
            *(float2*)&G[(size_t)rg * 256 + cl] = pk.f;
        }
    }
}

// ---------------------------------------------------------------- 3-NN + weights
__global__ __launch_bounds__(256) void knn_kernel(
    const float* __restrict__ xyz1, const float* __restrict__ xyz2,
    int* __restrict__ idxb, float* __restrict__ wb) {
    __shared__ float4 pts[2051];          // 4 regions of 513 (bank stagger)
    __shared__ float cd[64][4][3];
    __shared__ int   ci[64][4][3];
    int t = threadIdx.x;
    int bq = blockIdx.x;
    int b = bq >> 7;
    const float* x2b = xyz2 + (size_t)b * SS_PTS * 3;
    for (int j = t; j < SS_PTS; j += 256) {
        float x = x2b[j * 3 + 0], y = x2b[j * 3 + 1], z = x2b[j * 3 + 2];
        pts[(j >> 9) * 513 + (j & 511)] = make_float4(x, y, z, x * x + y * y + z * z);
    }
    int lq = t >> 2, p = t & 3;
    int g = bq * 64 + lq;
    float qx = xyz1[(size_t)g * 3 + 0];
    float qy = xyz1[(size_t)g * 3 + 1];
    float qz = xyz1[(size_t)g * 3 + 2];
    __syncthreads();

    float m2x = -2.0f * qx, m2y = -2.0f * qy, m2z = -2.0f * qz;
    float d0 = 3.4e38f, d1 = 3.4e38f, d2 = 3.4e38f;
    int j0 = 0, j1 = 0, j2 = 0;
    int base = p * 513, sbase = p * 512;
    #pragma unroll 4
    for (int s = 0; s < 512; ++s) {
        float4 pt = pts[base + s];
        float sc = fmaf(m2x, pt.x, fmaf(m2y, pt.y, fmaf(m2z, pt.z, pt.w)));
        if (sc < d2) {
            d2 = sc; j2 = sbase + s;
            if (d2 < d1) {
                float td = d1; d1 = d2; d2 = td;
                int tj = j1; j1 = j2; j2 = tj;
                if (d1 < d0) {
                    td = d0; d0 = d1; d1 = td;
                    tj = j0; j0 = j1; j1 = tj;
                }
            }
        }
    }
    cd[lq][p][0] = d0; cd[lq][p][1] = d1; cd[lq][p][2] = d2;
    ci[lq][p][0] = j0; ci[lq][p][1] = j1; ci[lq][p][2] = j2;
    __syncthreads();

    if (p == 0) {
        float e0 = 3.4e38f, e1 = 3.4e38f, e2 = 3.4e38f;
        int k0 = 0, k1 = 0, k2 = 0;
        #pragma unroll
        for (int pp = 0; pp < 4; ++pp)
            #pragma unroll
            for (int e = 0; e < 3; ++e) {
                float sc = cd[lq][pp][e];
                int sj = ci[lq][pp][e];
                if (sc < e2) {
                    e2 = sc; k2 = sj;
                    if (e2 < e1) {
                        float td = e1; e1 = e2; e2 = td;
                        int tj = k1; k1 = k2; k2 = tj;
                        if (e1 < e0) {
                            td = e0; e0 = e1; e1 = td;
                            tj = k0; k0 = k1; k1 = tj;
                        }
                    }
                }
            }
        float qq = qx * qx + qy * qy + qz * qz;
        float dd0 = fmaxf(e0 + qq, 1e-10f);
        float dd1 = fmaxf(e1 + qq, 1e-10f);
        float dd2 = fmaxf(e2 + qq, 1e-10f);
        float w0 = 1.0f / dd0, w1 = 1.0f / dd1, w2 = 1.0f / dd2;
        float inv = 1.0f / (w0 + w1 + w2);
        idxb[(size_t)g * 3 + 0] = k0;
        idxb[(size_t)g * 3 + 1] = k1;
        idxb[(size_t)g * 3 + 2] = k2;
        wb[(size_t)g * 3 + 0] = w0 * inv;
        wb[(size_t)g * 3 + 1] = w1 * inv;
        wb[(size_t)g * 3 + 2] = w2 * inv;
    }
}

// ---------------------------------------------------------------- GEMM1 v6
// h1[64 rows][256] = points1 @ W1a^T  (K=64 MFMA)  +  Sum_k w_k * G[idx_k]
// Gather hits G (bf16, 1 MB/batch); batch = bx&7 pins each batch to one XCD
// (round-robin block->XCD), so gathers are XCD-local-L2 hits.
__global__ __launch_bounds__(256, 3) void gemm1_kernel(
    const float* __restrict__ points1, const u16* __restrict__ G,
    const int* __restrict__ idxb, const float* __restrict__ wb,
    const u16* __restrict__ wt1b, u16* __restrict__ h1, float* __restrict__ part1) {
    __shared__ __align__(16) u16 Si[64 * 260];     // interp sums bf16
    __shared__ __align__(16) u16 Bs[8192];         // W1a tile 256x32, swizzled
    __shared__ int   idxs[192];
    __shared__ float wls[192];
    __shared__ float bsum[256], bsq[256];

    int t = threadIdx.x, bx = blockIdx.x;
    int batch = bx & 7;
    int R0 = batch * 8192 + (bx >> 3) * 64;
    const u16* Gb = G + (size_t)batch * SS_PTS * 256;

    if (t < 192) {
        idxs[t] = idxb[(size_t)R0 * 3 + t];
        wls[t]  = wb[(size_t)R0 * 3 + t];
    }
    bsum[t] = 0.0f; bsq[t] = 0.0f;
    __syncthreads();

    int w = t >> 6, l = t & 63, l15 = l & 15, q = l >> 4;
    int wr = (w >> 1) * 32, wc = (w & 1) * 128;

    // ---- phase 1: gather-sum from G into Si; one wave per query row
    {
        #pragma unroll 4
        for (int e = 0; e < 16; ++e) {
            int qi = w * 16 + e;
            int i0 = idxs[qi * 3 + 0], i1 = idxs[qi * 3 + 1], i2 = idxs[qi * 3 + 2];
            float w0 = wls[qi * 3 + 0], w1 = wls[qi * 3 + 1], w2 = wls[qi * 3 + 2];
            union { float2 f; u16 u[4]; } g0, g1, g2;
            g0.f = *(const float2*)(Gb + (size_t)i0 * 256 + l * 4);
            g1.f = *(const float2*)(Gb + (size_t)i1 * 256 + l * 4);
            g2.f = *(const float2*)(Gb + (size_t)i2 * 256 + l * 4);
            union { u16 u[4]; float2 f; } pk;
            #pragma unroll
            for (int i = 0; i < 4; ++i) {
                float v = fmaf(w0, bf2f(g0.u[i]),
                          fmaf(w1, bf2f(g1.u[i]), w2 * bf2f(g2.u[i])));
                pk.u[i] = f2bf(v);
            }
            *(float2*)&Si[qi * 260 + l * 4] = pk.f;
        }
    }

    // ---- B staging regs (W1a rows, k 0..63)
    int bm = t >> 1, bh = t & 1;
    int sb0 = (bm >> 1) & 3, sb1 = ((bm + 128) >> 1) & 3;
    const u16* wsrc0 = wt1b + (size_t)bm * 320 + bh * 16;
    const u16* wsrc1 = wt1b + (size_t)(bm + 128) * 320 + bh * 16;
    float4 pb0 = ((const float4*)wsrc0)[0], pb1 = ((const float4*)wsrc0)[1];
    float4 pb2 = ((const float4*)wsrc1)[0], pb3 = ((const float4*)wsrc1)[1];

    f32x4 acc[2][8];
    #pragma unroll
    for (int i = 0; i < 2; ++i)
        #pragma unroll
        for (int j = 0; j < 8; ++j) acc[i][j] = (f32x4){0.f, 0.f, 0.f, 0.f};

    // ---- phase 2: K-loop (2 x K=32) on points1 @ W1a^T
    #pragma unroll
    for (int kb = 0; kb < 2; ++kb) {
        *(float4*)&Bs[bm * 32 + (((bh * 2 + 0) ^ sb0) << 3)] = pb0;
        *(float4*)&Bs[bm * 32 + (((bh * 2 + 1) ^ sb0) << 3)] = pb1;
        *(float4*)&Bs[(bm + 128) * 32 + (((bh * 2 + 0) ^ sb1) << 3)] = pb2;
        *(float4*)&Bs[(bm + 128) * 32 + (((bh * 2 + 1) ^ sb1) << 3)] = pb3;
        __syncthreads();
        if (kb == 0) {
            pb0 = ((const float4*)(wsrc0 + 32))[0];
            pb1 = ((const float4*)(wsrc0 + 32))[1];
            pb2 = ((const float4*)(wsrc1 + 32))[0];
            pb3 = ((const float4*)(wsrc1 + 32))[1];
        }
        union uf { float4 f; bf16x8 v; };
        uf af[2], bf8[8];
        #pragma unroll
        for (int fi = 0; fi < 2; ++fi) {
            int ml = wr + fi * 16 + l15;
            const float* s = points1 + (size_t)(R0 + ml) * 64 + kb * 32 + q * 8;
            float4 x0 = ((const float4*)s)[0], x1 = ((const float4*)s)[1];
            float va[8] = {x0.x, x0.y, x0.z, x0.w, x1.x, x1.y, x1.z, x1.w};
            af[fi].f = pack8(va);
        }
        #pragma unroll
        for (int fj = 0; fj < 8; ++fj) {
            int nl = wc + fj * 16 + l15;
            bf8[fj].f = *(const float4*)&Bs[nl * 32 + ((q ^ ((nl >> 1) & 3)) << 3)];
        }
        #pragma unroll
        for (int fi = 0; fi < 2; ++fi)
            #pragma unroll
            for (int fj = 0; fj < 8; ++fj)
                acc[fi][fj] = __builtin_amdgcn_mfma_f32_16x16x32_bf16(
                    bf8[fj].v, af[fi].v, acc[fi][fj], 0, 0, 0);
        __syncthreads();
    }

    // ---- epilogue: add interp (Si), store h1 K-tiled, channel stats
    #pragma unroll
    for (int fi = 0; fi < 2; ++fi) {
        int rl = wr + fi * 16 + l15;
        int rg = R0 + rl;
        #pragma unroll
        for (int fj = 0; fj < 8; ++fj) {
            int c0 = wc + fj * 16 + q * 4;
            union { float2 f; u16 u[4]; } si;
            si.f = *(const float2*)&Si[rl * 260 + c0];
            float vv[4];
            union { u16 u[4]; float2 f; } pk;
            #pragma unroll
            for (int i = 0; i < 4; ++i) {
                vv[i] = acc[fi][fj][i] + bf2f(si.u[i]);
                pk.u[i] = f2bf(vv[i]);
            }
            *(float2*)&h1[((size_t)(c0 >> 5) * 65536 + rg) * 32 + (c0 & 31)] = pk.f;
            #pragma unroll
            for (int i = 0; i < 4; ++i) {
                atomicAdd(&bsum[c0 + i], vv[i]);
                atomicAdd(&bsq[c0 + i], vv[i] * vv[i]);
            }
        }
    }
    __syncthreads();
    part1[(size_t)bx * 512 + t * 2 + 0] = bsum[t];
    part1[(size_t)bx * 512 + t * 2 + 1] = bsq[t];
}

// ---------------------------------------------------------------- stats reduce
__global__ __launch_bounds__(256) void reduce_kernel(
    const float* __restrict__ part, int nblk, int C, float invM,
    const float* __restrict__ gam, const float* __restrict__ bet,
    float* __restrict__ st) {
    __shared__ float red[256];
    int t = threadIdx.x;
    int slot = t & 31, ig = t >> 5;
    int cb = blockIdx.x * 16;
    float p = 0.0f;
    for (int i = ig; i < nblk; i += 8)
        p += part[(size_t)i * (2 * C) + cb * 2 + slot];
    red[t] = p;
    __syncthreads();
    if (t < 32) {
        float tot = red[t];
        #pragma unroll
        for (int k = 1; k < 8; ++k) tot += red[k * 32 + t];
        red[t] = tot;
    }
    __syncthreads();
    if (t < 16) {
        int c = cb + t;
        float sum = red[2 * t], sq = red[2 * t + 1];
        float mean = sum * invM;
        float var  = sq * invM - mean * mean;
        float rs   = rsqrtf(var + 1e-5f);
        float scv  = gam[c] * rs;
        st[c]     = scv;
        st[C + c] = bet[c] - mean * scv;
    }
}

// ---------------------------------------------------------------- GEMM2 v5
// 64x128 tile, grid 1024. LDS double-buffer + reg prefetch, 1 barrier/iter.
__global__ __launch_bounds__(256, 4) void gemm2_kernel(
    const u16* __restrict__ h1, const u16* __restrict__ wt2b,
    const float* __restrict__ st1,
    u16* __restrict__ h2, float* __restrict__ part2) {
    __shared__ __align__(16) u16 As[2][64 * 32];
    __shared__ __align__(16) u16 Bs[2][128 * 32];
    __shared__ float sc1[256], sh1[256];
    __shared__ float bsum[128], bsq[128];

    int t = threadIdx.x;
    int bx = blockIdx.x;
    int R0 = bx * 64;
    sc1[t] = st1[t];
    sh1[t] = st1[256 + t];
    if (t < 128) { bsum[t] = 0.0f; bsq[t] = 0.0f; }

    int w = t >> 6, l = t & 63, l15 = l & 15, q = l >> 4;
    int wr = w * 16;
    int arow = t >> 2, ac8 = (t & 3) << 3, sa = (arow >> 1) & 3;
    int bm = t >> 1, bh = t & 1, sb = (bm >> 1) & 3;

    union lda_t { float4 f; u16 u[8]; };
    lda_t pa; float4 pb0, pb1;
    const u16* bsrc = wt2b + (size_t)bm * 256 + bh * 16;

    pa.f = *(const float4*)(h1 + ((size_t)0 * 65536 + R0 + arow) * 32 + ac8);
    pb0 = ((const float4*)bsrc)[0];
    pb1 = ((const float4*)bsrc)[1];

    f32x4 acc[8];
    #pragma unroll
    for (int j = 0; j < 8; ++j) acc[j] = (f32x4){0.f, 0.f, 0.f, 0.f};

    __syncthreads();   // sc1/sh1 visible

    {
        float o[8];
        #pragma unroll
        for (int j = 0; j < 8; ++j)
            o[j] = fmaxf(fmaf(bf2f(pa.u[j]), sc1[ac8 + j], sh1[ac8 + j]), 0.0f);
        *(float4*)&As[0][arow * 32 + (((ac8 >> 3) ^ sa) << 3)] = pack8(o);
        *(float4*)&Bs[0][bm * 32 + (((bh * 2 + 0) ^ sb) << 3)] = pb0;
        *(float4*)&Bs[0][bm * 32 + (((bh * 2 + 1) ^ sb) << 3)] = pb1;
    }
    __syncthreads();

    #pragma unroll
    for (int kb = 0; kb < 8; ++kb) {
        if (kb < 7) {
            pa.f = *(const float4*)(h1 + ((size_t)(kb + 1) * 65536 + R0 + arow) * 32 + ac8);
            pb0 = ((const float4*)(bsrc + (kb + 1) * 32))[0];
            pb1 = ((const float4*)(bsrc + (kb + 1) * 32))[1];
        }
        int buf = kb & 1;
        union uf { float4 f; bf16x8 v; };
        uf af, bf8[8];
        {
            int ml = wr + l15;
            af.f = *(const float4*)&As[buf][ml * 32 + ((q ^ ((ml >> 1) & 3)) << 3)];
        }
        #pragma unroll
        for (int fj = 0; fj < 8; ++fj) {
            int nl = fj * 16 + l15;
            bf8[fj].f = *(const float4*)&Bs[buf][nl * 32 + ((q ^ ((nl >> 1) & 3)) << 3)];
        }
        #pragma unroll
        for (int fj = 0; fj < 8; ++fj)
            acc[fj] = __builtin_amdgcn_mfma_f32_16x16x32_bf16(
                bf8[fj].v, af.v, acc[fj], 0, 0, 0);
        if (kb < 7) {
            int ch0 = (kb + 1) * 32 + ac8;
            float o[8];
            #pragma unroll
            for (int j = 0; j < 8; ++j)
                o[j] = fmaxf(fmaf(bf2f(pa.u[j]), sc1[ch0 + j], sh1[ch0 + j]), 0.0f);
            *(float4*)&As[buf ^ 1][arow * 32 + (((ac8 >> 3) ^ sa) << 3)] = pack8(o);
            *(float4*)&Bs[buf ^ 1][bm * 32 + (((bh * 2 + 0) ^ sb) << 3)] = pb0;
            *(float4*)&Bs[buf ^ 1][bm * 32 + (((bh * 2 + 1) ^ sb) << 3)] = pb1;
        }
        __syncthreads();
    }

    int rg = R0 + wr + l15;
    #pragma unroll
    for (int fj = 0; fj < 8; ++fj) {
        int cl = fj * 16 + q * 4;
        union { u16 u[4]; float2 f; } pk;
        #pragma unroll
        for (int i = 0; i < 4; ++i) pk.u[i] = f2bf(acc[fj][i]);
        *(float2*)&h2[(size_t)rg * 128 + cl] = pk.f;
    }
    #pragma unroll
    for (int fj = 0; fj < 8; ++fj)
        #pragma unroll
        for (int i = 0; i < 4; ++i) {
            float s = acc[fj][i];
            float sq = s * s;
            #pragma unroll
            for (int d = 1; d < 16; d <<= 1) {
                s  += __shfl_xor(s, d, 16);
                sq += __shfl_xor(sq, d, 16);
            }
            if (l15 == 0) {
                int cl = fj * 16 + q * 4 + i;
                atomicAdd(&bsum[cl], s);
                atomicAdd(&bsq[cl], sq);
            }
        }
    __syncthreads();
    if (t < 128) {
        part2[(size_t)bx * 256 + t * 2 + 0] = bsum[t];
        part2[(size_t)bx * 256 + t * 2 + 1] = bsq[t];
    }
}

// ---------------------------------------------------------------- final BN2 + relu
__global__ __launch_bounds__(256) void final_kernel(
    const u16* __restrict__ h2, const float* __restrict__ st2,
    float* __restrict__ out) {
    __shared__ float lst[256];
    int t = threadIdx.x;
    lst[t] = st2[t];
    __syncthreads();
    size_t e0 = ((size_t)blockIdx.x * 256 + t) * 8;
    int c0 = (int)(e0 & 127);
    union { float4 f; u16 u[8]; } ld;
    ld.f = *(const float4*)(h2 + e0);
    float o[8];
    #pragma unroll
    for (int j = 0; j < 8; ++j) {
        int c = c0 + j;
        float v = fmaf(bf2f(ld.u[j]), lst[c], lst[128 + c]);
        o[j] = fmaxf(v, 0.0f);
    }
    float4* op = (float4*)(out + e0);
    float4 r0; r0.x = o[0]; r0.y = o[1]; r0.z = o[2]; r0.w = o[3];
    float4 r1; r1.x = o[4]; r1.y = o[5]; r1.z = o[6]; r1.w = o[7];
    op[0] = r0;
    op[1] = r1;
}

// ----------------------------------------------------------------
extern "C" void kernel_launch(void* const* d_in, const int* in_sizes, int n_in,
                              void* d_out, int out_size, void* d_ws, size_t ws_size,
                              hipStream_t stream) {
    (void)in_sizes; (void)n_in; (void)out_size; (void)ws_size;
    const float* xyz1    = (const float*)d_in[0];
    const float* xyz2    = (const float*)d_in[1];
    const float* points1 = (const float*)d_in[2];
    const float* points2 = (const float*)d_in[3];
    const float* W1      = (const float*)d_in[4];
    const float* g1      = (const float*)d_in[5];
    const float* b1      = (const float*)d_in[6];
    const float* W2      = (const float*)d_in[7];
    const float* g2      = (const float*)d_in[8];
    const float* b2      = (const float*)d_in[9];

    char* ws = (char*)d_ws;
    int*   idxb = (int*)(ws + OFF_IDX);
    float* wb   = (float*)(ws + OFF_W);
    u16*   wt1b = (u16*)(ws + OFF_WT1B);
    u16*   wt2b = (u16*)(ws + OFF_WT2B);
    float* st1  = (float*)(ws + OFF_ST1);
    float* st2  = (float*)(ws + OFF_ST2);
    float* p1   = (float*)(ws + OFF_P1);
    float* p2   = (float*)(ws + OFF_P2);
    u16*   h1   = (u16*)(ws + OFF_H1);
    u16*   h2   = (u16*)(ws + OFF_H2);
    u16*   G    = (u16*)(ws + OFF_H2);   // reuse: consumed before h2 is written
    float* outp = (float*)d_out;

    prep_kernel<<<320, 256, 0, stream>>>(W1, W2, wt1b, wt2b);
    gemm0_kernel<<<256, 256, 0, stream>>>(points2, wt1b, G);
    knn_kernel<<<1024, 256, 0, stream>>>(xyz1, xyz2, idxb, wb);
    gemm1_kernel<<<1024, 256, 0, stream>>>(points1, G, idxb, wb, wt1b, h1, p1);
    reduce_kernel<<<16, 256, 0, stream>>>(p1, 1024, 256, 1.0f / 65536.0f, g1, b1, st1);
    gemm2_kernel<<<1024, 256, 0, stream>>>(h1, wt2b, st1, h2, p2);
    reduce_kernel<<<8, 256, 0, stream>>>(p2, 1024, 128, 1.0f / 65536.0f, g2, b2, st2);
    final_kernel<<<4096, 256, 0, stream>>>(h2, st2, outp);
}

// Round 7
// 316.801 us; speedup vs baseline: 1.6453x; 1.6453x over previous
//
#include <hip/hip_runtime.h>
#include <hip/hip_bf16.h>

typedef unsigned short u16;
typedef short bf16x8 __attribute__((ext_vector_type(8)));   // 8 bf16 = 4 VGPRs
typedef float f32x4 __attribute__((ext_vector_type(4)));

#define SS_PTS 2048

// workspace byte offsets (all 16B-aligned)
#define OFF_IDX   0ULL         // int  [65536*3]
#define OFF_W     786432ULL    // f32  [65536*3]
#define OFF_WT1B  1572864ULL   // bf16 [256][320]
#define OFF_WT2B  1736704ULL   // bf16 [128][256]
#define OFF_ST1   1802240ULL   // f32  [512]
#define OFF_ST2   1804288ULL   // f32  [256]
#define OFF_P1    1805312ULL   // f32  [1024][512]
#define OFF_P2    3902464ULL   // f32  [1024][256]
#define OFF_H1    4950016ULL   // bf16 tiled [8][65536][32]
#define OFF_H2    38504448ULL  // bf16 [65536][128]; ALSO G [16384][256] bf16
                               // (G consumed by gemm1 before gemm2 writes h2)

__device__ __forceinline__ u16 f2bf(float x) {
    union { __hip_bfloat16 h; u16 u; } cv;
    cv.h = __float2bfloat16(x);
    return cv.u;
}
__device__ __forceinline__ float bf2f(u16 u) {
    union { unsigned int i; float f; } cv;
    cv.i = ((unsigned int)u) << 16;
    return cv.f;
}
__device__ __forceinline__ float4 pack8(const float* v) {
    union { u16 u[8]; float4 f; } pk;
    #pragma unroll
    for (int j = 0; j < 8; ++j) pk.u[j] = f2bf(v[j]);
    return pk.f;
}

// ---------------------------------------------------------------- prep: W -> bf16
__global__ __launch_bounds__(256) void prep_kernel(
    const float* __restrict__ W1, const float* __restrict__ W2,
    u16* __restrict__ wt1b, u16* __restrict__ wt2b) {
    int i = blockIdx.x * 256 + threadIdx.x;
    if (i < 81920) wt1b[i] = f2bf(W1[i]);
    if (i < 32768) wt2b[i] = f2bf(W2[i]);
}

// ---------------------------------------------------------------- GEMM0
// G[16384][256] = points2[16384][256] @ W1b^T  (W1b = wt1b cols 64..319)
__global__ __launch_bounds__(256) void gemm0_kernel(
    const float* __restrict__ points2, const u16* __restrict__ wt1b,
    u16* __restrict__ G) {
    __shared__ __align__(16) u16 Bs[8192];   // 256 rows x 32 k, XOR-swizzled

    int t = threadIdx.x, bx = blockIdx.x;
    int R0 = bx * 64;
    int w = t >> 6, l = t & 63, l15 = l & 15, q = l >> 4;
    int wr = (w >> 1) * 32, wc = (w & 1) * 128;
    int bm = t >> 1, bh = t & 1;
    int sb0 = (bm >> 1) & 3, sb1 = ((bm + 128) >> 1) & 3;
    const u16* wsrc0 = wt1b + (size_t)bm * 320 + 64 + bh * 16;
    const u16* wsrc1 = wt1b + (size_t)(bm + 128) * 320 + 64 + bh * 16;

    float4 pb0 = ((const float4*)wsrc0)[0], pb1 = ((const float4*)wsrc0)[1];
    float4 pb2 = ((const float4*)wsrc1)[0], pb3 = ((const float4*)wsrc1)[1];

    f32x4 acc[2][8];
    #pragma unroll
    for (int i = 0; i < 2; ++i)
        #pragma unroll
        for (int j = 0; j < 8; ++j) acc[i][j] = (f32x4){0.f, 0.f, 0.f, 0.f};

    #pragma unroll
    for (int kb = 0; kb < 8; ++kb) {
        *(float4*)&Bs[bm * 32 + (((bh * 2 + 0) ^ sb0) << 3)] = pb0;
        *(float4*)&Bs[bm * 32 + (((bh * 2 + 1) ^ sb0) << 3)] = pb1;
        *(float4*)&Bs[(bm + 128) * 32 + (((bh * 2 + 0) ^ sb1) << 3)] = pb2;
        *(float4*)&Bs[(bm + 128) * 32 + (((bh * 2 + 1) ^ sb1) << 3)] = pb3;
        __syncthreads();
        if (kb < 7) {
            pb0 = ((const float4*)(wsrc0 + (kb + 1) * 32))[0];
            pb1 = ((const float4*)(wsrc0 + (kb + 1) * 32))[1];
            pb2 = ((const float4*)(wsrc1 + (kb + 1) * 32))[0];
            pb3 = ((const float4*)(wsrc1 + (kb + 1) * 32))[1];
        }
        union uf { float4 f; bf16x8 v; };
        uf af[2], bf8[8];
        #pragma unroll
        for (int fi = 0; fi < 2; ++fi) {
            int ml = wr + fi * 16 + l15;
            const float* s = points2 + (size_t)(R0 + ml) * 256 + kb * 32 + q * 8;
            float4 x0 = ((const float4*)s)[0], x1 = ((const float4*)s)[1];
            float va[8] = {x0.x, x0.y, x0.z, x0.w, x1.x, x1.y, x1.z, x1.w};
            af[fi].f = pack8(va);
        }
        #pragma unroll
        for (int fj = 0; fj < 8; ++fj) {
            int nl = wc + fj * 16 + l15;
            bf8[fj].f = *(const float4*)&Bs[nl * 32 + ((q ^ ((nl >> 1) & 3)) << 3)];
        }
        #pragma unroll
        for (int fi = 0; fi < 2; ++fi)
            #pragma unroll
            for (int fj = 0; fj < 8; ++fj)
                acc[fi][fj] = __builtin_amdgcn_mfma_f32_16x16x32_bf16(
                    bf8[fj].v, af[fi].v, acc[fi][fj], 0, 0, 0);
        __syncthreads();
    }

    #pragma unroll
    for (int fi = 0; fi < 2; ++fi) {
        int rg = R0 + wr + fi * 16 + l15;
        #pragma unroll
        for (int fj = 0; fj < 8; ++fj) {
            int cl = wc + fj * 16 + q * 4;
            union { u16 u[4]; float2 f; } pk;
            #pragma unroll
            for (int i = 0; i < 4; ++i) pk.u[i] = f2bf(acc[fi][fj][i]);
            *(float2*)&G[(size_t)rg * 256 + cl] = pk.f;
        }
    }
}

// ---------------------------------------------------------------- 3-NN + weights
__global__ __launch_bounds__(256) void knn_kernel(
    const float* __restrict__ xyz1, const float* __restrict__ xyz2,
    int* __restrict__ idxb, float* __restrict__ wb) {
    __shared__ float4 pts[2051];          // 4 regions of 513 (bank stagger)
    __shared__ float cd[64][4][3];
    __shared__ int   ci[64][4][3];
    int t = threadIdx.x;
    int bq = blockIdx.x;
    int b = bq >> 7;
    const float* x2b = xyz2 + (size_t)b * SS_PTS * 3;
    for (int j = t; j < SS_PTS; j += 256) {
        float x = x2b[j * 3 + 0], y = x2b[j * 3 + 1], z = x2b[j * 3 + 2];
        pts[(j >> 9) * 513 + (j & 511)] = make_float4(x, y, z, x * x + y * y + z * z);
    }
    int lq = t >> 2, p = t & 3;
    int g = bq * 64 + lq;
    float qx = xyz1[(size_t)g * 3 + 0];
    float qy = xyz1[(size_t)g * 3 + 1];
    float qz = xyz1[(size_t)g * 3 + 2];
    __syncthreads();

    float m2x = -2.0f * qx, m2y = -2.0f * qy, m2z = -2.0f * qz;
    float d0 = 3.4e38f, d1 = 3.4e38f, d2 = 3.4e38f;
    int j0 = 0, j1 = 0, j2 = 0;
    int base = p * 513, sbase = p * 512;
    #pragma unroll 4
    for (int s = 0; s < 512; ++s) {
        float4 pt = pts[base + s];
        float sc = fmaf(m2x, pt.x, fmaf(m2y, pt.y, fmaf(m2z, pt.z, pt.w)));
        if (sc < d2) {
            d2 = sc; j2 = sbase + s;
            if (d2 < d1) {
                float td = d1; d1 = d2; d2 = td;
                int tj = j1; j1 = j2; j2 = tj;
                if (d1 < d0) {
                    td = d0; d0 = d1; d1 = td;
                    tj = j0; j0 = j1; j1 = tj;
                }
            }
        }
    }
    cd[lq][p][0] = d0; cd[lq][p][1] = d1; cd[lq][p][2] = d2;
    ci[lq][p][0] = j0; ci[lq][p][1] = j1; ci[lq][p][2] = j2;
    __syncthreads();

    if (p == 0) {
        float e0 = 3.4e38f, e1 = 3.4e38f, e2 = 3.4e38f;
        int k0 = 0, k1 = 0, k2 = 0;
        #pragma unroll
        for (int pp = 0; pp < 4; ++pp)
            #pragma unroll
            for (int e = 0; e < 3; ++e) {
                float sc = cd[lq][pp][e];
                int sj = ci[lq][pp][e];
                if (sc < e2) {
                    e2 = sc; k2 = sj;
                    if (e2 < e1) {
                        float td = e1; e1 = e2; e2 = td;
                        int tj = k1; k1 = k2; k2 = tj;
                        if (e1 < e0) {
                            td = e0; e0 = e1; e1 = td;
                            tj = k0; k0 = k1; k1 = tj;
                        }
                    }
                }
            }
        float qq = qx * qx + qy * qy + qz * qz;
        float dd0 = fmaxf(e0 + qq, 1e-10f);
        float dd1 = fmaxf(e1 + qq, 1e-10f);
        float dd2 = fmaxf(e2 + qq, 1e-10f);
        float w0 = 1.0f / dd0, w1 = 1.0f / dd1, w2 = 1.0f / dd2;
        float inv = 1.0f / (w0 + w1 + w2);
        idxb[(size_t)g * 3 + 0] = k0;
        idxb[(size_t)g * 3 + 1] = k1;
        idxb[(size_t)g * 3 + 2] = k2;
        wb[(size_t)g * 3 + 0] = w0 * inv;
        wb[(size_t)g * 3 + 1] = w1 * inv;
        wb[(size_t)g * 3 + 2] = w2 * inv;
    }
}

// ---------------------------------------------------------------- GEMM1 v7
// h1 = points1 @ W1a^T (K=64 MFMA) + Sum_k w_k * G[idx_k].
// v7: NO LDS atomics — stats via shfl-reduce over the 16 row-lanes into
// per-wave-pair LDS slices (each slot written by exactly one lane).
// idx/w read via uniform-address broadcast loads (no LDS staging).
__global__ __launch_bounds__(256, 3) void gemm1_kernel(
    const float* __restrict__ points1, const u16* __restrict__ G,
    const int* __restrict__ idxb, const float* __restrict__ wb,
    const u16* __restrict__ wt1b, u16* __restrict__ h1, float* __restrict__ part1) {
    __shared__ __align__(16) u16 Si[64 * 258];     // interp bf16, stride 258
    __shared__ __align__(16) u16 Bs[8192];         // W1a tile 256x32, swizzled
    __shared__ float bsum[2][256], bsq[2][256];    // per-wave-pair slices

    int t = threadIdx.x, bx = blockIdx.x;
    int batch = bx & 7;
    int R0 = batch * 8192 + (bx >> 3) * 64;
    const u16* Gb = G + (size_t)batch * SS_PTS * 256;

    int w = t >> 6, l = t & 63, l15 = l & 15, q = l >> 4;
    int wr = (w >> 1) * 32, wc = (w & 1) * 128;

    // ---- phase 1: gather-sum from G into Si; one wave per query row
    {
        #pragma unroll 4
        for (int e = 0; e < 16; ++e) {
            int qi = w * 16 + e;
            size_t gq = (size_t)(R0 + qi) * 3;
            int i0 = idxb[gq + 0], i1 = idxb[gq + 1], i2 = idxb[gq + 2];
            float w0 = wb[gq + 0], w1 = wb[gq + 1], w2 = wb[gq + 2];
            union { float2 f; u16 u[4]; } g0, g1, g2;
            g0.f = *(const float2*)(Gb + (size_t)i0 * 256 + l * 4);
            g1.f = *(const float2*)(Gb + (size_t)i1 * 256 + l * 4);
            g2.f = *(const float2*)(Gb + (size_t)i2 * 256 + l * 4);
            union { u16 u[4]; float2 f; } pk;
            #pragma unroll
            for (int i = 0; i < 4; ++i) {
                float v = fmaf(w0, bf2f(g0.u[i]),
                          fmaf(w1, bf2f(g1.u[i]), w2 * bf2f(g2.u[i])));
                pk.u[i] = f2bf(v);
            }
            *(float2*)&Si[qi * 258 + l * 4] = pk.f;
        }
    }

    // ---- B staging regs (W1a rows, k 0..63)
    int bm = t >> 1, bh = t & 1;
    int sb0 = (bm >> 1) & 3, sb1 = ((bm + 128) >> 1) & 3;
    const u16* wsrc0 = wt1b + (size_t)bm * 320 + bh * 16;
    const u16* wsrc1 = wt1b + (size_t)(bm + 128) * 320 + bh * 16;
    float4 pb0 = ((const float4*)wsrc0)[0], pb1 = ((const float4*)wsrc0)[1];
    float4 pb2 = ((const float4*)wsrc1)[0], pb3 = ((const float4*)wsrc1)[1];

    f32x4 acc[2][8];
    #pragma unroll
    for (int i = 0; i < 2; ++i)
        #pragma unroll
        for (int j = 0; j < 8; ++j) acc[i][j] = (f32x4){0.f, 0.f, 0.f, 0.f};

    // ---- phase 2: K-loop (2 x K=32) on points1 @ W1a^T
    #pragma unroll
    for (int kb = 0; kb < 2; ++kb) {
        *(float4*)&Bs[bm * 32 + (((bh * 2 + 0) ^ sb0) << 3)] = pb0;
        *(float4*)&Bs[bm * 32 + (((bh * 2 + 1) ^ sb0) << 3)] = pb1;
        *(float4*)&Bs[(bm + 128) * 32 + (((bh * 2 + 0) ^ sb1) << 3)] = pb2;
        *(float4*)&Bs[(bm + 128) * 32 + (((bh * 2 + 1) ^ sb1) << 3)] = pb3;
        __syncthreads();
        if (kb == 0) {
            pb0 = ((const float4*)(wsrc0 + 32))[0];
            pb1 = ((const float4*)(wsrc0 + 32))[1];
            pb2 = ((const float4*)(wsrc1 + 32))[0];
            pb3 = ((const float4*)(wsrc1 + 32))[1];
        }
        union uf { float4 f; bf16x8 v; };
        uf af[2], bf8[8];
        #pragma unroll
        for (int fi = 0; fi < 2; ++fi) {
            int ml = wr + fi * 16 + l15;
            const float* s = points1 + (size_t)(R0 + ml) * 64 + kb * 32 + q * 8;
            float4 x0 = ((const float4*)s)[0], x1 = ((const float4*)s)[1];
            float va[8] = {x0.x, x0.y, x0.z, x0.w, x1.x, x1.y, x1.z, x1.w};
            af[fi].f = pack8(va);
        }
        #pragma unroll
        for (int fj = 0; fj < 8; ++fj) {
            int nl = wc + fj * 16 + l15;
            bf8[fj].f = *(const float4*)&Bs[nl * 32 + ((q ^ ((nl >> 1) & 3)) << 3)];
        }
        #pragma unroll
        for (int fi = 0; fi < 2; ++fi)
            #pragma unroll
            for (int fj = 0; fj < 8; ++fj)
                acc[fi][fj] = __builtin_amdgcn_mfma_f32_16x16x32_bf16(
                    bf8[fj].v, af[fi].v, acc[fi][fj], 0, 0, 0);
        __syncthreads();
    }

    // ---- epilogue: add interp (Si), store h1 K-tiled, stats via shfl (no atomics)
    #pragma unroll
    for (int fj = 0; fj < 8; ++fj) {
        int c0 = wc + fj * 16 + q * 4;
        float s[4], sq[4];
        #pragma unroll
        for (int i = 0; i < 4; ++i) { s[i] = 0.0f; sq[i] = 0.0f; }
        #pragma unroll
        for (int fi = 0; fi < 2; ++fi) {
            int rl = wr + fi * 16 + l15;
            int rg = R0 + rl;
            union { float2 f; u16 u[4]; } si;
            si.f = *(const float2*)&Si[rl * 258 + c0];
            union { u16 u[4]; float2 f; } pk;
            #pragma unroll
            for (int i = 0; i < 4; ++i) {
                float v = acc[fi][fj][i] + bf2f(si.u[i]);
                pk.u[i] = f2bf(v);
                s[i] += v; sq[i] += v * v;
            }
            *(float2*)&h1[((size_t)(c0 >> 5) * 65536 + rg) * 32 + (c0 & 31)] = pk.f;
        }
        #pragma unroll
        for (int i = 0; i < 4; ++i) {
            #pragma unroll
            for (int d = 1; d < 16; d <<= 1) {
                s[i]  += __shfl_xor(s[i], d, 16);
                sq[i] += __shfl_xor(sq[i], d, 16);
            }
        }
        if (l15 == 0) {
            int half = w >> 1;
            #pragma unroll
            for (int i = 0; i < 4; ++i) {
                bsum[half][c0 + i] = s[i];
                bsq[half][c0 + i]  = sq[i];
            }
        }
    }
    __syncthreads();
    part1[(size_t)bx * 512 + t * 2 + 0] = bsum[0][t] + bsum[1][t];
    part1[(size_t)bx * 512 + t * 2 + 1] = bsq[0][t] + bsq[1][t];
}

// ---------------------------------------------------------------- stats reduce
__global__ __launch_bounds__(256) void reduce_kernel(
    const float* __restrict__ part, int nblk, int C, float invM,
    const float* __restrict__ gam, const float* __restrict__ bet,
    float* __restrict__ st) {
    __shared__ float red[256];
    int t = threadIdx.x;
    int slot = t & 31, ig = t >> 5;
    int cb = blockIdx.x * 16;
    float p = 0.0f;
    for (int i = ig; i < nblk; i += 8)
        p += part[(size_t)i * (2 * C) + cb * 2 + slot];
    red[t] = p;
    __syncthreads();
    if (t < 32) {
        float tot = red[t];
        #pragma unroll
        for (int k = 1; k < 8; ++k) tot += red[k * 32 + t];
        red[t] = tot;
    }
    __syncthreads();
    if (t < 16) {
        int c = cb + t;
        float sum = red[2 * t], sq = red[2 * t + 1];
        float mean = sum * invM;
        float var  = sq * invM - mean * mean;
        float rs   = rsqrtf(var + 1e-5f);
        float scv  = gam[c] * rs;
        st[c]     = scv;
        st[C + c] = bet[c] - mean * scv;
    }
}

// ---------------------------------------------------------------- GEMM2 v7
// 64x128 tile, grid 1024, LDS dbuf + reg prefetch. Stats: shfl + per-wave
// LDS slices (no atomics).
__global__ __launch_bounds__(256, 4) void gemm2_kernel(
    const u16* __restrict__ h1, const u16* __restrict__ wt2b,
    const float* __restrict__ st1,
    u16* __restrict__ h2, float* __restrict__ part2) {
    __shared__ __align__(16) u16 As[2][64 * 32];
    __shared__ __align__(16) u16 Bs[2][128 * 32];
    __shared__ float sc1[256], sh1[256];
    __shared__ float bsum2[4][128], bsq2[4][128];

    int t = threadIdx.x;
    int bx = blockIdx.x;
    int R0 = bx * 64;
    sc1[t] = st1[t];
    sh1[t] = st1[256 + t];

    int w = t >> 6, l = t & 63, l15 = l & 15, q = l >> 4;
    int wr = w * 16;
    int arow = t >> 2, ac8 = (t & 3) << 3, sa = (arow >> 1) & 3;
    int bm = t >> 1, bh = t & 1, sb = (bm >> 1) & 3;

    union lda_t { float4 f; u16 u[8]; };
    lda_t pa; float4 pb0, pb1;
    const u16* bsrc = wt2b + (size_t)bm * 256 + bh * 16;

    pa.f = *(const float4*)(h1 + ((size_t)0 * 65536 + R0 + arow) * 32 + ac8);
    pb0 = ((const float4*)bsrc)[0];
    pb1 = ((const float4*)bsrc)[1];

    f32x4 acc[8];
    #pragma unroll
    for (int j = 0; j < 8; ++j) acc[j] = (f32x4){0.f, 0.f, 0.f, 0.f};

    __syncthreads();   // sc1/sh1 visible

    {
        float o[8];
        #pragma unroll
        for (int j = 0; j < 8; ++j)
            o[j] = fmaxf(fmaf(bf2f(pa.u[j]), sc1[ac8 + j], sh1[ac8 + j]), 0.0f);
        *(float4*)&As[0][arow * 32 + (((ac8 >> 3) ^ sa) << 3)] = pack8(o);
        *(float4*)&Bs[0][bm * 32 + (((bh * 2 + 0) ^ sb) << 3)] = pb0;
        *(float4*)&Bs[0][bm * 32 + (((bh * 2 + 1) ^ sb) << 3)] = pb1;
    }
    __syncthreads();

    #pragma unroll
    for (int kb = 0; kb < 8; ++kb) {
        if (kb < 7) {
            pa.f = *(const float4*)(h1 + ((size_t)(kb + 1) * 65536 + R0 + arow) * 32 + ac8);
            pb0 = ((const float4*)(bsrc + (kb + 1) * 32))[0];
            pb1 = ((const float4*)(bsrc + (kb + 1) * 32))[1];
        }
        int buf = kb & 1;
        union uf { float4 f; bf16x8 v; };
        uf af, bf8[8];
        {
            int ml = wr + l15;
            af.f = *(const float4*)&As[buf][ml * 32 + ((q ^ ((ml >> 1) & 3)) << 3)];
        }
        #pragma unroll
        for (int fj = 0; fj < 8; ++fj) {
            int nl = fj * 16 + l15;
            bf8[fj].f = *(const float4*)&Bs[buf][nl * 32 + ((q ^ ((nl >> 1) & 3)) << 3)];
        }
        #pragma unroll
        for (int fj = 0; fj < 8; ++fj)
            acc[fj] = __builtin_amdgcn_mfma_f32_16x16x32_bf16(
                bf8[fj].v, af.v, acc[fj], 0, 0, 0);
        if (kb < 7) {
            int ch0 = (kb + 1) * 32 + ac8;
            float o[8];
            #pragma unroll
            for (int j = 0; j < 8; ++j)
                o[j] = fmaxf(fmaf(bf2f(pa.u[j]), sc1[ch0 + j], sh1[ch0 + j]), 0.0f);
            *(float4*)&As[buf ^ 1][arow * 32 + (((ac8 >> 3) ^ sa) << 3)] = pack8(o);
            *(float4*)&Bs[buf ^ 1][bm * 32 + (((bh * 2 + 0) ^ sb) << 3)] = pb0;
            *(float4*)&Bs[buf ^ 1][bm * 32 + (((bh * 2 + 1) ^ sb) << 3)] = pb1;
        }
        __syncthreads();
    }

    // ---- epilogue: h2 store + stats via shfl into per-wave slices (no atomics)
    int rg = R0 + wr + l15;
    #pragma unroll
    for (int fj = 0; fj < 8; ++fj) {
        int cl = fj * 16 + q * 4;
        union { u16 u[4]; float2 f; } pk;
        float s[4], sq[4];
        #pragma unroll
        for (int i = 0; i < 4; ++i) {
            float v = acc[fj][i];
            pk.u[i] = f2bf(v);
            s[i] = v; sq[i] = v * v;
        }
        *(float2*)&h2[(size_t)rg * 128 + cl] = pk.f;
        #pragma unroll
        for (int i = 0; i < 4; ++i) {
            #pragma unroll
            for (int d = 1; d < 16; d <<= 1) {
                s[i]  += __shfl_xor(s[i], d, 16);
                sq[i] += __shfl_xor(sq[i], d, 16);
            }
        }
        if (l15 == 0) {
            #pragma unroll
            for (int i = 0; i < 4; ++i) {
                bsum2[w][cl + i] = s[i];
                bsq2[w][cl + i]  = sq[i];
            }
        }
    }
    __syncthreads();
    if (t < 128) {
        part2[(size_t)bx * 256 + t * 2 + 0] =
            bsum2[0][t] + bsum2[1][t] + bsum2[2][t] + bsum2[3][t];
        part2[(size_t)bx * 256 + t * 2 + 1] =
            bsq2[0][t] + bsq2[1][t] + bsq2[2][t] + bsq2[3][t];
    }
}

// ---------------------------------------------------------------- final BN2 + relu
__global__ __launch_bounds__(256) void final_kernel(
    const u16* __restrict__ h2, const float* __restrict__ st2,
    float* __restrict__ out) {
    __shared__ float lst[256];
    int t = threadIdx.x;
    lst[t] = st2[t];
    __syncthreads();
    size_t e0 = ((size_t)blockIdx.x * 256 + t) * 8;
    int c0 = (int)(e0 & 127);
    union { float4 f; u16 u[8]; } ld;
    ld.f = *(const float4*)(h2 + e0);
    float o[8];
    #pragma unroll
    for (int j = 0; j < 8; ++j) {
        int c = c0 + j;
        float v = fmaf(bf2f(ld.u[j]), lst[c], lst[128 + c]);
        o[j] = fmaxf(v, 0.0f);
    }
    float4* op = (float4*)(out + e0);
    float4 r0; r0.x = o[0]; r0.y = o[1]; r0.z = o[2]; r0.w = o[3];
    float4 r1; r1.x = o[4]; r1.y = o[5]; r1.z = o[6]; r1.w = o[7];
    op[0] = r0;
    op[1] = r1;
}

// ----------------------------------------------------------------
extern "C" void kernel_launch(void* const* d_in, const int* in_sizes, int n_in,
                              void* d_out, int out_size, void* d_ws, size_t ws_size,
                              hipStream_t stream) {
    (void)in_sizes; (void)n_in; (void)out_size; (void)ws_size;
    const float* xyz1    = (const float*)d_in[0];
    const float* xyz2    = (const float*)d_in[1];
    const float* points1 = (const float*)d_in[2];
    const float* points2 = (const float*)d_in[3];
    const float* W1      = (const float*)d_in[4];
    const float* g1      = (const float*)d_in[5];
    const float* b1      = (const float*)d_in[6];
    const float* W2      = (const float*)d_in[7];
    const float* g2      = (const float*)d_in[8];
    const float* b2      = (const float*)d_in[9];

    char* ws = (char*)d_ws;
    int*   idxb = (int*)(ws + OFF_IDX);
    float* wb   = (float*)(ws + OFF_W);
    u16*   wt1b = (u16*)(ws + OFF_WT1B);
    u16*   wt2b = (u16*)(ws + OFF_WT2B);
    float* st1  = (float*)(ws + OFF_ST1);
    float* st2  = (float*)(ws + OFF_ST2);
    float* p1   = (float*)(ws + OFF_P1);
    float* p2   = (float*)(ws + OFF_P2);
    u16*   h1   = (u16*)(ws + OFF_H1);
    u16*   h2   = (u16*)(ws + OFF_H2);
    u16*   G    = (u16*)(ws + OFF_H2);   // reuse: consumed before h2 is written
    float* outp = (float*)d_out;

    prep_kernel<<<320, 256, 0, stream>>>(W1, W2, wt1b, wt2b);
    gemm0_kernel<<<256, 256, 0, stream>>>(points2, wt1b, G);
    knn_kernel<<<1024, 256, 0, stream>>>(xyz1, xyz2, idxb, wb);
    gemm1_kernel<<<1024, 256, 0, stream>>>(points1, G, idxb, wb, wt1b, h1, p1);
    reduce_kernel<<<16, 256, 0, stream>>>(p1, 1024, 256, 1.0f / 65536.0f, g1, b1, st1);
    gemm2_kernel<<<1024, 256, 0, stream>>>(h1, wt2b, st1, h2, p2);
    reduce_kernel<<<8, 256, 0, stream>>>(p2, 1024, 128, 1.0f / 65536.0f, g2, b2, st2);
    final_kernel<<<4096, 256, 0, stream>>>(h2, st2, outp);
}